// Round 8
// baseline (644.638 us; speedup 1.0000x reference)
//
#include <hip/hip_runtime.h>

#define BB 64
#define TT 72
#define SS 72
#define EE 128
#define HH 256
#define VV 32000
#define KK 512
#define NB 4          // lstm blocks (one XCD)
#define NATTN 64      // attn blocks (one per batch)
#define NGEMM 188     // gemm blocks: 25 n-lanes x 7-8 blocks

using f32x4  = __attribute__((ext_vector_type(4))) float;
using short8 = __attribute__((ext_vector_type(8))) short;
typedef unsigned long long u64;

__device__ __forceinline__ unsigned short f2bf(float f) {
  unsigned u = __float_as_uint(f);
  unsigned r = (u + 0x7fffu + ((u >> 16) & 1u)) >> 16;
  return (unsigned short)r;
}
__device__ __forceinline__ float bf2f(unsigned short b) {
  return __uint_as_float(((unsigned)b) << 16);
}
__device__ __forceinline__ float sigm(float x) { return 1.f / (1.f + __expf(-x)); }
__device__ __forceinline__ float tanh_f(float x) { return 1.f - 2.f / (__expf(2.f * x) + 1.f); }

__device__ __forceinline__ float wsum(float v) {
  v += __shfl_xor(v, 1, 64);  v += __shfl_xor(v, 2, 64);  v += __shfl_xor(v, 4, 64);
  v += __shfl_xor(v, 8, 64);  v += __shfl_xor(v, 16, 64); v += __shfl_xor(v, 32, 64);
  return v;
}
__device__ __forceinline__ float wmax(float v) {
  v = fmaxf(v, __shfl_xor(v, 1, 64));  v = fmaxf(v, __shfl_xor(v, 2, 64));
  v = fmaxf(v, __shfl_xor(v, 4, 64));  v = fmaxf(v, __shfl_xor(v, 8, 64));
  v = fmaxf(v, __shfl_xor(v, 16, 64)); v = fmaxf(v, __shfl_xor(v, 32, 64));
  return v;
}
__device__ __forceinline__ void g2l16(const void* g, void* l) {
  __builtin_amdgcn_global_load_lds((const __attribute__((address_space(1))) void*)g,
                                   (__attribute__((address_space(3))) void*)l, 16, 0, 0);
}
__device__ __forceinline__ uint4 pack8(const float4 v0, const float4 v1) {
  uint4 o;
  o.x = f2bf(v0.x) | ((unsigned)f2bf(v0.y) << 16);
  o.y = f2bf(v0.z) | ((unsigned)f2bf(v0.w) << 16);
  o.z = f2bf(v1.x) | ((unsigned)f2bf(v1.y) << 16);
  o.w = f2bf(v1.z) | ((unsigned)f2bf(v1.w) << 16);
  return o;
}
__device__ __forceinline__ u64 aload(const u64* p) {
  return __hip_atomic_load(p, __ATOMIC_RELAXED, __HIP_MEMORY_SCOPE_AGENT);
}
__device__ __forceinline__ void astore(u64* p, u64 v) {
  __hip_atomic_store(p, v, __ATOMIC_RELAXED, __HIP_MEMORY_SCOPE_AGENT);
}

// ------------------------------------------------------------------ prep:
// blocks [0,18): gather xembt [t][kcx][b] 16B entries; [18,256): cvt wlin16
__global__ void prep_kernel(const int* __restrict__ tok, const float* __restrict__ emb,
                            const float* __restrict__ Wlin,
                            uint4* __restrict__ xembt, unsigned short* __restrict__ wlin16) {
  const int bid = blockIdx.x, tid = threadIdx.x;
  if (bid < 18) {
    for (int e = bid * 256 + tid; e < TT * 16 * 64; e += 18 * 256) {
      const int b = e & 63, kcx = (e >> 6) & 15, t = e >> 10;
      const int tk = tok[b * TT + t];
      const float4* s = (const float4*)(emb + (size_t)tk * EE + kcx * 8);
      xembt[e] = pack8(s[0], s[1]);
    }
  } else {
    const int n4 = (VV * KK) / 4;
    for (int i = (bid - 18) * 256 + tid; i < n4; i += 238 * 256) {
      float4 v = ((const float4*)Wlin)[i];
      ushort4 o;
      o.x = f2bf(v.x); o.y = f2bf(v.y); o.z = f2bf(v.z); o.w = f2bf(v.w);
      ((ushort4*)wlin16)[i] = o;
    }
  }
}

// ------------------------------------------------------------------ mega:
// 256 blocks x 512 thr, 1 block/CU (LDS 114688). Roles: 4 lstm (one XCD),
// 64 attn, 188 gemm. Data visibility: producer atomic-store + flag; consumers
// read with PLAIN loads after flag (safe: lines never touched pre-flag within
// a run; across graph replays stale lines hold identical values).
__global__ __launch_bounds__(512) void mega_kernel(
    const float* __restrict__ h0, const float* __restrict__ c0,
    const float* __restrict__ Wih, const float* __restrict__ Whh,
    const float* __restrict__ bih, const float* __restrict__ bhh,
    const float* __restrict__ enc, const int* __restrict__ lens,
    const float* __restrict__ blin, const uint4* __restrict__ xembt,
    const unsigned short* __restrict__ wlin16,
    uint4* __restrict__ hex, unsigned int* __restrict__ sync,
    u64* __restrict__ hcat64, float* __restrict__ out) {
  __shared__ __align__(16) char smem[114688];
  __shared__ int s_role;

  const int tid = threadIdx.x;
  unsigned int* flags1 = sync;        // [0..3] lstm step counters
  unsigned int* F2     = sync + 8;    // [0..71] attn completion counters (per t)
  unsigned int* elect  = sync + 96;   // [0..7] arrivals, [8] winner, [9] roleCtr

  // ---- role election ----
  if (tid == 0) {
    unsigned xcd;
    asm volatile("s_getreg_b32 %0, hwreg(20, 0, 8)" : "=s"(xcd));
    xcd &= 7;
    int role = -1;
    const unsigned my = __hip_atomic_fetch_add(elect + xcd, 1u,
                          __ATOMIC_RELAXED, __HIP_MEMORY_SCOPE_AGENT);
    if (my < NB) {
      if (my == NB - 1) {
        unsigned exp = 0;
        __hip_atomic_compare_exchange_strong(elect + 8, &exp, xcd + 1,
            __ATOMIC_RELAXED, __ATOMIC_RELAXED, __HIP_MEMORY_SCOPE_AGENT);
      }
      unsigned wv;
      while ((wv = __hip_atomic_load(elect + 8, __ATOMIC_RELAXED,
                                     __HIP_MEMORY_SCOPE_AGENT)) == 0)
        __builtin_amdgcn_s_sleep(1);
      if (wv == xcd + 1) role = (int)my;
    }
    if (role < 0) {
      const unsigned idx = __hip_atomic_fetch_add(elect + 9, 1u,
                             __ATOMIC_RELAXED, __HIP_MEMORY_SCOPE_AGENT);
      role = (idx < NATTN) ? (100 + (int)idx) : (1000 + (int)(idx - NATTN));
    }
    s_role = role;
  }
  __syncthreads();
  const int role = s_role;

  if (role < NB) {
    // ============================ LSTM (round-5 core; hex only) =============
    const int bk = role;
    uint4* hx = (uint4*)smem;                // 48*64 entries (49152 B)
    uint4* xw = (uint4*)(smem + 49152);      // 4096 entries (65536 B)
    const int ln = tid & 63, w = tid >> 6;
    const int n16 = ln & 15, kgrp = ln >> 4;
    const int wj = w >> 1, wb = w & 1;
    u64* hexq = (u64*)hex;

    short8 wf[4][8];
    f32x4 biasf[4];
    {
      const int jrow = bk * 64 + wj * 16;
#pragma unroll
      for (int g = 0; g < 4; ++g) {
        const int row = g * HH + jrow + n16;
#pragma unroll
        for (int kt = 0; kt < 8; ++kt) {
          const float* src = Whh + (size_t)row * HH + kt * 32 + kgrp * 8;
          const float4 v0 = ((const float4*)src)[0];
          const float4 v1 = ((const float4*)src)[1];
          short8 wv;
          wv[0]=(short)f2bf(v0.x); wv[1]=(short)f2bf(v0.y); wv[2]=(short)f2bf(v0.z); wv[3]=(short)f2bf(v0.w);
          wv[4]=(short)f2bf(v1.x); wv[5]=(short)f2bf(v1.y); wv[6]=(short)f2bf(v1.z); wv[7]=(short)f2bf(v1.w);
          wf[g][kt] = wv;
        }
        const int r4 = g * HH + jrow + kgrp * 4;
        const float4 bi = *(const float4*)(bih + r4);
        const float4 bh = *(const float4*)(bhh + r4);
        biasf[g] = (f32x4){bi.x + bh.x, bi.y + bh.y, bi.z + bh.z, bi.w + bh.w};
      }
    }
#pragma unroll
    for (int i = 0; i < 8; ++i) {
      const int e = i * 512 + tid;
      const int en = e & 15, ek = (e >> 4) & 3, ewj = (e >> 6) & 3,
                ekt = (e >> 8) & 3, eg = e >> 10;
      const int row = eg * HH + bk * 64 + ewj * 16 + en;
      const float* src = Wih + (size_t)row * EE + ekt * 32 + ek * 8;
      xw[e] = pack8(((const float4*)src)[0], ((const float4*)src)[1]);
    }
    float creg[2][4];
#pragma unroll
    for (int mt = 0; mt < 2; ++mt)
#pragma unroll
      for (int r = 0; r < 4; ++r)
        creg[mt][r] = c0[(size_t)((wb * 2 + mt) * 16 + n16) * HH + bk * 64 + wj * 16 + kgrp * 4 + r];
#pragma unroll
    for (int i = 0; i < 4; ++i) {
      const int e = i * 512 + tid;
      const int kc = e >> 6, b = e & 63;
      const float* src = h0 + (size_t)b * HH + kc * 8;
      hx[kc * 64 + b] = pack8(((const float4*)src)[0], ((const float4*)src)[1]);
    }
    __syncthreads();

    const int kcq  = bk * 8 + wj * 2 + (kgrp >> 1);
    const int half = kgrp & 1;

    for (int t = 0; t < TT; ++t) {
#pragma unroll
      for (int i = 0; i < 2; ++i) {
        const int e = (i * 8 + w) * 64 + ln;
        g2l16(xembt + (size_t)t * 1024 + e, (char*)&hx[32 * 64] + e * 16);
      }
      if (t > 0) {
        if (tid < NB) {
          while (__hip_atomic_load(flags1 + tid, __ATOMIC_RELAXED,
                                   __HIP_MEMORY_SCOPE_AGENT) < (unsigned)t)
            __builtin_amdgcn_s_sleep(1);
        }
        __syncthreads();
#pragma unroll
        for (int i = 0; i < 4; ++i) {
          const int e = (i * 8 + w) * 64 + ln;
          g2l16(hex + (size_t)t * 2048 + e, (char*)hx + e * 16);
        }
      }
      __syncthreads();   // drains vmcnt(0): hx staged

      f32x4 acc[4][2];
#pragma unroll
      for (int g = 0; g < 4; ++g)
#pragma unroll
        for (int mt = 0; mt < 2; ++mt)
          acc[g][mt] = biasf[g];

#pragma unroll
      for (int kt = 0; kt < 8; ++kt) {
#pragma unroll
        for (int mt = 0; mt < 2; ++mt) {
          const short8 b = *(const short8*)&hx[(kt * 4 + kgrp) * 64 + (wb * 2 + mt) * 16 + n16];
          acc[0][mt] = __builtin_amdgcn_mfma_f32_16x16x32_bf16(wf[0][kt], b, acc[0][mt], 0, 0, 0);
          acc[1][mt] = __builtin_amdgcn_mfma_f32_16x16x32_bf16(wf[1][kt], b, acc[1][mt], 0, 0, 0);
          acc[2][mt] = __builtin_amdgcn_mfma_f32_16x16x32_bf16(wf[2][kt], b, acc[2][mt], 0, 0, 0);
          acc[3][mt] = __builtin_amdgcn_mfma_f32_16x16x32_bf16(wf[3][kt], b, acc[3][mt], 0, 0, 0);
        }
      }
#pragma unroll
      for (int kti = 0; kti < 4; ++kti) {
        short8 wx[4];
#pragma unroll
        for (int g = 0; g < 4; ++g)
          wx[g] = *(const short8*)&xw[(((g * 4 + kti) * 4 + wj) * 4 + kgrp) * 16 + n16];
#pragma unroll
        for (int mt = 0; mt < 2; ++mt) {
          const short8 b = *(const short8*)&hx[(32 + kti * 4 + kgrp) * 64 + (wb * 2 + mt) * 16 + n16];
#pragma unroll
          for (int g = 0; g < 4; ++g)
            acc[g][mt] = __builtin_amdgcn_mfma_f32_16x16x32_bf16(wx[g], b, acc[g][mt], 0, 0, 0);
        }
      }

#pragma unroll
      for (int mt = 0; mt < 2; ++mt) {
        u64 pk = 0;
#pragma unroll
        for (int r = 0; r < 4; ++r) {
          const float iv = acc[0][mt][r], fv = acc[1][mt][r],
                      gv = acc[2][mt][r], ov = acc[3][mt][r];
          const float cn = sigm(fv) * creg[mt][r] + sigm(iv) * tanh_f(gv);
          creg[mt][r] = cn;
          const float hv = sigm(ov) * tanh_f(cn);
          pk |= (u64)f2bf(hv) << (16 * r);
        }
        const int batch = (wb * 2 + mt) * 16 + n16;
        astore(hexq + ((size_t)((t + 1) * 32 + kcq) * 64 + batch) * 2 + half, pk);
      }
      asm volatile("s_waitcnt vmcnt(0)" ::: "memory");
      __syncthreads();
      if (tid == 0)
        __hip_atomic_store(flags1 + bk, (unsigned)(t + 1),
                           __ATOMIC_RELAXED, __HIP_MEMORY_SCOPE_AGENT);
    }
  } else if (role < 1000) {
    // ============================ ATTN (one block per batch) ================
    const int b = role - 100;
    float* enc_s = (float*)smem;              // 73728 B
    float* h_s   = (float*)(smem + 73728);    // 1024 B
    float* at_s  = (float*)(smem + 74752);    // 288 B
    float* ctx_s = (float*)(smem + 75776);    // 1024 B
    const int wv8 = tid >> 6, ln = tid & 63;
    const int len = lens[b];
    const u64* hexq = (const u64*)hex;
    {
      const float4* src = (const float4*)(enc + (size_t)b * SS * HH);
      float4* dst = (float4*)enc_s;
      for (int i = tid; i < SS * HH / 4; i += 512) dst[i] = src[i];
    }
    __syncthreads();

    for (int t = 0; t < TT; ++t) {
      if (tid < NB) {
        while (__hip_atomic_load(flags1 + tid, __ATOMIC_RELAXED,
                                 __HIP_MEMORY_SCOPE_AGENT) < (unsigned)(t + 1))
          __builtin_amdgcn_s_sleep(2);
      }
      __syncthreads();
      if (tid < 64) {
        const int kc = tid >> 1, hf = tid & 1;
        const u64 v = aload(hexq + ((size_t)((t + 1) * 32 + kc) * 64 + b) * 2 + hf);
        const int j0 = kc * 8 + hf * 4;
        h_s[j0]     = bf2f((unsigned short)v);
        h_s[j0 + 1] = bf2f((unsigned short)(v >> 16));
        h_s[j0 + 2] = bf2f((unsigned short)(v >> 32));
        h_s[j0 + 3] = bf2f((unsigned short)(v >> 48));
        astore(hcat64 + (size_t)(t * 64 + b) * 128 + tid, v);   // h-half of hcat
      }
      __syncthreads();

      const float4 hv = ((const float4*)h_s)[ln];
      for (int s = wv8; s < SS; s += 8) {
        const float4 ev = ((const float4*)(enc_s + s * HH))[ln];
        float p = hv.x * ev.x + hv.y * ev.y + hv.z * ev.z + hv.w * ev.w;
        p = wsum(p);
        if (ln == 0) at_s[s] = p * 0.0625f;
      }
      __syncthreads();
      if (wv8 == 0) {
        const float v0 = (ln < len) ? at_s[ln] : -3.0e38f;
        const bool has1 = (ln < 8) && (64 + ln < len);
        const float v1 = has1 ? at_s[64 + ln] : -3.0e38f;
        const float m = wmax(fmaxf(v0, v1));
        const float e0 = (ln < len) ? __expf(v0 - m) : 0.f;
        const float e1 = has1 ? __expf(v1 - m) : 0.f;
        const float inv = 1.f / wsum(e0 + e1);
        at_s[ln] = e0 * inv;
        if (ln < 8) at_s[64 + ln] = e1 * inv;
      }
      __syncthreads();
      if (tid < HH) {
        float acc = 0.f;
#pragma unroll 8
        for (int s = 0; s < SS; ++s) acc += at_s[s] * enc_s[s * HH + tid];
        ctx_s[tid] = acc;
      }
      __syncthreads();
      if (tid < 64) {
        const u64 pk = (u64)f2bf(ctx_s[tid * 4])
                     | ((u64)f2bf(ctx_s[tid * 4 + 1]) << 16)
                     | ((u64)f2bf(ctx_s[tid * 4 + 2]) << 32)
                     | ((u64)f2bf(ctx_s[tid * 4 + 3]) << 48);
        astore(hcat64 + (size_t)(t * 64 + b) * 128 + 64 + tid, pk);
      }
      asm volatile("s_waitcnt vmcnt(0)" ::: "memory");
      __syncthreads();
      if (tid == 0)
        __hip_atomic_fetch_add(F2 + t, 1u, __ATOMIC_RELAXED, __HIP_MEMORY_SCOPE_AGENT);
    }
  } else {
    // ============================ GEMM (per-t 64x256 tiles, n-lane sched) ===
    // As: 65536 B, swizzled [64 rows][1024 B], slot ^= (row&7)
    // Bs: 2 x 16384 B per-kt slices, [256 rows][64 B], slot ^= (row&3)
    const int gid = role - 1000;
    char* Bsb = smem + 65536;
    const int ln = tid & 63, w = tid >> 6;
    const int n16 = ln & 15, kgrp = ln >> 4;
    const int lane = gid % 25;                 // n-lane: cols [lane*1280, +1280)
    const int sub  = gid / 25;
    const int nbl  = (lane < 13) ? 8 : 7;

    for (int t = sub; t < TT; t += nbl) {
      if (tid == 0) {
        while (__hip_atomic_load(F2 + t, __ATOMIC_RELAXED, __HIP_MEMORY_SCOPE_AGENT) < NATTN)
          __builtin_amdgcn_s_sleep(8);
      }
      __syncthreads();   // also fences previous item's LDS reads vs stageA

      // ---- stage A (64 x 512 bf16) once, source-permuted for swizzle ----
#pragma unroll
      for (int i = 0; i < 8; ++i) {
        const int s = i * 512 + tid;           // 16B slot
        const int row = s >> 6, off = s & 63;
        const size_t src = (size_t)t * 65536 + ((size_t)row << 10)
                         + ((size_t)(off ^ (row & 7)) << 4);
        g2l16((const char*)hcat64 + src, smem + s * 16);
      }

      for (int nt2 = 0; nt2 < 5; ++nt2) {
        const int nbase = (lane * 5 + nt2) * 256;
        float bs[2];
#pragma unroll
        for (int fn = 0; fn < 2; ++fn) bs[fn] = blin[nbase + w * 32 + fn * 16 + n16];

        // stage B kt=0 into buf0
#pragma unroll
        for (int i = 0; i < 2; ++i) {
          const int s = i * 512 + tid;
          const int row = s >> 2, sl = s & 3;
          const size_t src = ((size_t)(nbase + row) << 10) + ((size_t)(sl ^ (row & 3)) << 4);
          g2l16((const char*)wlin16 + src, Bsb + s * 16);
        }
        __syncthreads();   // A + B0 ready

        f32x4 acc[4][2] = {};
        for (int kt = 0; kt < 16; ++kt) {
          const int cur = kt & 1;
          if (kt < 15) {
            const int nxt = cur ^ 1;
#pragma unroll
            for (int i = 0; i < 2; ++i) {
              const int s = i * 512 + tid;
              const int row = s >> 2, sl = s & 3;
              const size_t src = ((size_t)(nbase + row) << 10) + (size_t)((kt + 1) << 6)
                               + ((size_t)(sl ^ (row & 3)) << 4);
              g2l16((const char*)wlin16 + src, Bsb + nxt * 16384 + s * 16);
            }
          }
          short8 af[4], bf[2];
#pragma unroll
          for (int f = 0; f < 4; ++f) {
            const int row = f * 16 + n16;
            af[f] = *(const short8*)(smem + (row << 10)
                      + ((((kt << 2) + kgrp) ^ (row & 7)) << 4));
          }
#pragma unroll
          for (int fn = 0; fn < 2; ++fn) {
            const int rr = w * 32 + fn * 16 + n16;
            bf[fn] = *(const short8*)(Bsb + cur * 16384 + (rr << 6)
                      + ((kgrp ^ (rr & 3)) << 4));
          }
#pragma unroll
          for (int fm = 0; fm < 4; ++fm)
#pragma unroll
            for (int fn = 0; fn < 2; ++fn)
              acc[fm][fn] = __builtin_amdgcn_mfma_f32_16x16x32_bf16(af[fm], bf[fn], acc[fm][fn], 0, 0, 0);
          __syncthreads();
        }

        // ---- epilogue: batch = fm*16 + (ln>>4)*4 + r, out[b][t][n] ----
#pragma unroll
        for (int fm = 0; fm < 4; ++fm) {
          const int b0 = fm * 16 + (ln >> 4) * 4;
#pragma unroll
          for (int fn = 0; fn < 2; ++fn) {
            const int n = nbase + w * 32 + fn * 16 + n16;
            float* cp = out + ((size_t)b0 * TT + t) * VV + n;
#pragma unroll
            for (int r = 0; r < 4; ++r) cp[(size_t)r * TT * VV] = acc[fm][fn][r] + bs[fn];
          }
        }
      }
    }
  }
}

// ------------------------------------------------------------------
extern "C" void kernel_launch(void* const* d_in, const int* in_sizes, int n_in,
                              void* d_out, int out_size, void* d_ws, size_t ws_size,
                              hipStream_t stream) {
  const int*   tok  = (const int*)  d_in[0];
  const float* enc  = (const float*)d_in[1];
  const int*   lens = (const int*)  d_in[2];
  const float* h0   = (const float*)d_in[3];
  const float* c0   = (const float*)d_in[4];
  const float* emb  = (const float*)d_in[5];
  const float* Wih  = (const float*)d_in[6];
  const float* Whh  = (const float*)d_in[7];
  const float* bih  = (const float*)d_in[8];
  const float* bhh  = (const float*)d_in[9];
  const float* Wlin = (const float*)d_in[10];
  const float* blin = (const float*)d_in[11];

  char* ws = (char*)d_ws;
  unsigned short* wlin16 = (unsigned short*)(ws);               // 32,768,000 B
  u64*            hcat64 = (u64*)           (ws + 32768000);    //  4,718,592 B [t*64+b][128 u64]
  uint4*          xembt  = (uint4*)         (ws + 37486592);    //  1,179,648 B
  uint4*          hex    = (uint4*)         (ws + 38666240);    //  2,392,064 B
  unsigned int*   sync   = (unsigned int*)  (ws + 41058304);    //        512 B
  float* out = (float*)d_out;

  hipMemsetAsync(sync, 0, 512, stream);
  prep_kernel<<<256, 256, 0, stream>>>(tok, emb, Wlin, xembt, wlin16);
  mega_kernel<<<256, 512, 0, stream>>>(h0, c0, Wih, Whh, bih, bhh, enc, lens,
                                       blin, xembt, wlin16, hex, sync, hcat64, out);
}

// Round 9
// 546.371 us; speedup vs baseline: 1.1799x; 1.1799x over previous
//
#include <hip/hip_runtime.h>

#define BB 64
#define TT 72
#define SS 72
#define EE 128
#define HH 256
#define VV 32000
#define KK 512
#define NB 8          // lstm blocks (one XCD)
#define NATTN 64      // attn blocks (one per batch)
#define NGEMM 184     // gemm blocks
#define NNT2 63       // n-tiles of 512 cols (last one padded)
#define NITEM (36 * NNT2)

using f32x4  = __attribute__((ext_vector_type(4))) float;
using short8 = __attribute__((ext_vector_type(8))) short;
typedef unsigned long long u64;

__device__ __forceinline__ unsigned short f2bf(float f) {
  unsigned u = __float_as_uint(f);
  unsigned r = (u + 0x7fffu + ((u >> 16) & 1u)) >> 16;
  return (unsigned short)r;
}
__device__ __forceinline__ float bf2f(unsigned short b) {
  return __uint_as_float(((unsigned)b) << 16);
}
__device__ __forceinline__ float sigm(float x) { return 1.f / (1.f + __expf(-x)); }
__device__ __forceinline__ float tanh_f(float x) { return 1.f - 2.f / (__expf(2.f * x) + 1.f); }

__device__ __forceinline__ float wsum(float v) {
  v += __shfl_xor(v, 1, 64);  v += __shfl_xor(v, 2, 64);  v += __shfl_xor(v, 4, 64);
  v += __shfl_xor(v, 8, 64);  v += __shfl_xor(v, 16, 64); v += __shfl_xor(v, 32, 64);
  return v;
}
__device__ __forceinline__ float wmax(float v) {
  v = fmaxf(v, __shfl_xor(v, 1, 64));  v = fmaxf(v, __shfl_xor(v, 2, 64));
  v = fmaxf(v, __shfl_xor(v, 4, 64));  v = fmaxf(v, __shfl_xor(v, 8, 64));
  v = fmaxf(v, __shfl_xor(v, 16, 64)); v = fmaxf(v, __shfl_xor(v, 32, 64));
  return v;
}
__device__ __forceinline__ void g2l16(const void* g, void* l) {
  __builtin_amdgcn_global_load_lds((const __attribute__((address_space(1))) void*)g,
                                   (__attribute__((address_space(3))) void*)l, 16, 0, 0);
}
__device__ __forceinline__ uint4 pack8(const float4 v0, const float4 v1) {
  uint4 o;
  o.x = f2bf(v0.x) | ((unsigned)f2bf(v0.y) << 16);
  o.y = f2bf(v0.z) | ((unsigned)f2bf(v0.w) << 16);
  o.z = f2bf(v1.x) | ((unsigned)f2bf(v1.y) << 16);
  o.w = f2bf(v1.z) | ((unsigned)f2bf(v1.w) << 16);
  return o;
}
__device__ __forceinline__ u64 aload(const u64* p) {
  return __hip_atomic_load(p, __ATOMIC_RELAXED, __HIP_MEMORY_SCOPE_AGENT);
}
__device__ __forceinline__ void astore(u64* p, u64 v) {
  __hip_atomic_store(p, v, __ATOMIC_RELAXED, __HIP_MEMORY_SCOPE_AGENT);
}

// ------------------------------------------------------------------ prep
__global__ void prep_kernel(const int* __restrict__ tok, const float* __restrict__ emb,
                            const float* __restrict__ Wlin,
                            uint4* __restrict__ xembt, unsigned short* __restrict__ wlin16) {
  const int bid = blockIdx.x, tid = threadIdx.x;
  if (bid < 18) {
    for (int e = bid * 256 + tid; e < TT * 16 * 64; e += 18 * 256) {
      const int b = e & 63, kcx = (e >> 6) & 15, t = e >> 10;
      const int tk = tok[b * TT + t];
      const float4* s = (const float4*)(emb + (size_t)tk * EE + kcx * 8);
      xembt[e] = pack8(s[0], s[1]);
    }
  } else {
    const int n4 = (VV * KK) / 4;
    for (int i = (bid - 18) * 256 + tid; i < n4; i += 238 * 256) {
      float4 v = ((const float4*)Wlin)[i];
      ushort4 o;
      o.x = f2bf(v.x); o.y = f2bf(v.y); o.z = f2bf(v.z); o.w = f2bf(v.w);
      ((ushort4*)wlin16)[i] = o;
    }
  }
}

// ------------------------------------------------------------------ mega
// 256 blocks x 512 thr, LDS 90112 => 1 block/CU => all co-resident.
// Roles: 8 lstm (one XCD), 64 attn, 184 gemm.
__global__ __launch_bounds__(512) void mega_kernel(
    const float* __restrict__ h0, const float* __restrict__ c0,
    const float* __restrict__ Wih, const float* __restrict__ Whh,
    const float* __restrict__ bih, const float* __restrict__ bhh,
    const float* __restrict__ enc, const int* __restrict__ lens,
    const float* __restrict__ blin, const uint4* __restrict__ xembt,
    const unsigned short* __restrict__ wlin16,
    uint4* __restrict__ hex, unsigned int* __restrict__ sync,
    u64* __restrict__ hcat64, float* __restrict__ out) {
  __shared__ __align__(16) char smem[90112];
  __shared__ int s_role;

  const int tid = threadIdx.x;
  unsigned int* flags1 = sync;         // [bk*32] lstm step counters (128B spaced)
  unsigned int* F2     = sync + 256;   // [0..71] attn completion counters
  unsigned int* elect  = sync + 336;   // [0..7] arrivals, [8] winner, [9] roleCtr

  if (tid == 0) {
    unsigned xcd;
    asm volatile("s_getreg_b32 %0, hwreg(20, 0, 8)" : "=s"(xcd));
    xcd &= 7;
    int role = -1;
    const unsigned my = __hip_atomic_fetch_add(elect + xcd, 1u,
                          __ATOMIC_RELAXED, __HIP_MEMORY_SCOPE_AGENT);
    if (my < NB) {
      if (my == NB - 1) {
        unsigned exp = 0;
        __hip_atomic_compare_exchange_strong(elect + 8, &exp, xcd + 1,
            __ATOMIC_RELAXED, __ATOMIC_RELAXED, __HIP_MEMORY_SCOPE_AGENT);
      }
      unsigned wv;
      while ((wv = __hip_atomic_load(elect + 8, __ATOMIC_RELAXED,
                                     __HIP_MEMORY_SCOPE_AGENT)) == 0)
        __builtin_amdgcn_s_sleep(1);
      if (wv == xcd + 1) role = (int)my;
    }
    if (role < 0) {
      const unsigned idx = __hip_atomic_fetch_add(elect + 9, 1u,
                             __ATOMIC_RELAXED, __HIP_MEMORY_SCOPE_AGENT);
      role = (idx < NATTN) ? (100 + (int)idx) : (1000 + (int)(idx - NATTN));
    }
    s_role = role;
  }
  __syncthreads();
  const int role = s_role;

  if (role < NB) {
    // ========================== LSTM: 8 blocks, 32 j each =================
    // hx LDS: [kc 0..47][b 0..63] 16B entries; kc<32 = h (K 0..255), kc>=32 = x.
    // Wave (wj=w>>2, wb=w&3): 4 gates x 16 j x 16 batches. wf[4][12] in VGPR.
    const int bk = role;
    uint4* hx = (uint4*)smem;                 // 49152 B
    float* biasL = (float*)(smem + 49152);    // 512 B
    const int ln = tid & 63, w = tid >> 6;
    const int n16 = ln & 15, kgrp = ln >> 4;
    const int wj = w >> 2, wb = w & 3;
    u64* hexq = (u64*)hex;

    short8 wf[4][12];
#pragma unroll
    for (int g = 0; g < 4; ++g) {
      const int row = g * HH + bk * 32 + wj * 16 + n16;
#pragma unroll
      for (int kt = 0; kt < 12; ++kt) {
        const float* src = (kt < 8) ? (Whh + (size_t)row * HH + kt * 32 + kgrp * 8)
                                    : (Wih + (size_t)row * EE + (kt - 8) * 32 + kgrp * 8);
        const float4 v0 = ((const float4*)src)[0];
        const float4 v1 = ((const float4*)src)[1];
        short8 wv;
        wv[0]=(short)f2bf(v0.x); wv[1]=(short)f2bf(v0.y); wv[2]=(short)f2bf(v0.z); wv[3]=(short)f2bf(v0.w);
        wv[4]=(short)f2bf(v1.x); wv[5]=(short)f2bf(v1.y); wv[6]=(short)f2bf(v1.z); wv[7]=(short)f2bf(v1.w);
        wf[g][kt] = wv;
      }
    }
    if (tid < 128) {
      const int wj2 = tid >> 6, kg2 = (tid >> 4) & 3, g2 = (tid >> 2) & 3, r2 = tid & 3;
      const int row = g2 * HH + bk * 32 + wj2 * 16 + kg2 * 4 + r2;
      biasL[tid] = bih[row] + bhh[row];
    }
    const int batch = wb * 16 + n16;
    const int j0 = bk * 32 + wj * 16 + kgrp * 4;
    float creg[4];
    {
      const float4 cv = *(const float4*)(c0 + (size_t)batch * HH + j0);
      creg[0] = cv.x; creg[1] = cv.y; creg[2] = cv.z; creg[3] = cv.w;
    }
#pragma unroll
    for (int i = 0; i < 4; ++i) {
      const int e = i * 512 + tid;
      const int kc = e >> 6, b = e & 63;
      const float* src = h0 + (size_t)b * HH + kc * 8;
      hx[kc * 64 + b] = pack8(((const float4*)src)[0], ((const float4*)src)[1]);
    }
    __syncthreads();

    const int kcq  = bk * 4 + wj * 2 + (kgrp >> 1);
    const int half = kgrp & 1;

    for (int t = 0; t < TT; ++t) {
      // x prefetch (16 KB) before the poll
#pragma unroll
      for (int i = 0; i < 2; ++i) {
        const int e = i * 512 + w * 64 + ln;
        g2l16(xembt + (size_t)t * 1024 + e, (char*)hx + (size_t)(2048 + e) * 16);
      }
      if (t > 0) {
        if (tid < NB) {
          while (__hip_atomic_load(flags1 + tid * 32, __ATOMIC_RELAXED,
                                   __HIP_MEMORY_SCOPE_AGENT) < (unsigned)t)
            __builtin_amdgcn_s_sleep(1);
        }
        __syncthreads();
#pragma unroll
        for (int i = 0; i < 4; ++i) {
          const int e = i * 512 + w * 64 + ln;
          g2l16(hex + (size_t)t * 2048 + e, (char*)hx + (size_t)e * 16);
        }
      }
      __syncthreads();   // drains vmcnt(0): hx staged

      f32x4 a0 = {0,0,0,0}, a1 = a0, a2 = a0, a3 = a0;
#pragma unroll
      for (int kt = 0; kt < 12; ++kt) {
        const short8 b = *(const short8*)&hx[(kt * 4 + kgrp) * 64 + batch];
        a0 = __builtin_amdgcn_mfma_f32_16x16x32_bf16(wf[0][kt], b, a0, 0, 0, 0);
        a1 = __builtin_amdgcn_mfma_f32_16x16x32_bf16(wf[1][kt], b, a1, 0, 0, 0);
        a2 = __builtin_amdgcn_mfma_f32_16x16x32_bf16(wf[2][kt], b, a2, 0, 0, 0);
        a3 = __builtin_amdgcn_mfma_f32_16x16x32_bf16(wf[3][kt], b, a3, 0, 0, 0);
      }
      const float4 b0 = *(const float4*)&biasL[wj * 64 + kgrp * 16 + 0];
      const float4 b1 = *(const float4*)&biasL[wj * 64 + kgrp * 16 + 4];
      const float4 b2 = *(const float4*)&biasL[wj * 64 + kgrp * 16 + 8];
      const float4 b3 = *(const float4*)&biasL[wj * 64 + kgrp * 16 + 12];
      const float bi[4] = {b0.x, b0.y, b0.z, b0.w};
      const float bf_[4] = {b1.x, b1.y, b1.z, b1.w};
      const float bg[4] = {b2.x, b2.y, b2.z, b2.w};
      const float bo[4] = {b3.x, b3.y, b3.z, b3.w};
      u64 pk = 0;
#pragma unroll
      for (int r = 0; r < 4; ++r) {
        const float iv = a0[r] + bi[r], fv = a1[r] + bf_[r],
                    gv = a2[r] + bg[r], ov = a3[r] + bo[r];
        const float cn = sigm(fv) * creg[r] + sigm(iv) * tanh_f(gv);
        creg[r] = cn;
        const float hv = sigm(ov) * tanh_f(cn);
        pk |= (u64)f2bf(hv) << (16 * r);
      }
      astore(hexq + ((size_t)(t + 1) * 2048 + kcq * 64 + batch) * 2 + half, pk);
      asm volatile("s_waitcnt vmcnt(0)" ::: "memory");
      __syncthreads();
      if (tid == 0)
        __hip_atomic_store(flags1 + bk * 32, (unsigned)(t + 1),
                           __ATOMIC_RELAXED, __HIP_MEMORY_SCOPE_AGENT);
    }
  } else if (role < 1000) {
    // ========================== ATTN (one block per batch) ================
    const int b = role - 100;
    float* enc_s = (float*)smem;
    float* h_s   = (float*)(smem + 73728);
    float* at_s  = (float*)(smem + 74752);
    float* ctx_s = (float*)(smem + 75776);
    const int wv8 = tid >> 6, ln = tid & 63;
    const int len = lens[b];
    const u64* hexq = (const u64*)hex;
    {
      const float4* src = (const float4*)(enc + (size_t)b * SS * HH);
      float4* dst = (float4*)enc_s;
      for (int i = tid; i < SS * HH / 4; i += 512) dst[i] = src[i];
    }
    __syncthreads();

    for (int t = 0; t < TT; ++t) {
      if (tid < NB) {
        while (__hip_atomic_load(flags1 + tid * 32, __ATOMIC_RELAXED,
                                 __HIP_MEMORY_SCOPE_AGENT) < (unsigned)(t + 1))
          __builtin_amdgcn_s_sleep(1);
      }
      __syncthreads();
      if (tid < 64) {
        const int kc = tid >> 1, hf = tid & 1;
        const u64 v = aload(hexq + ((size_t)(t + 1) * 2048 + kc * 64 + b) * 2 + hf);
        const int j0 = kc * 8 + hf * 4;
        h_s[j0]     = bf2f((unsigned short)v);
        h_s[j0 + 1] = bf2f((unsigned short)(v >> 16));
        h_s[j0 + 2] = bf2f((unsigned short)(v >> 32));
        h_s[j0 + 3] = bf2f((unsigned short)(v >> 48));
        astore(hcat64 + (size_t)(t * 64 + b) * 128 + tid, v);   // h-half of hcat
      }
      __syncthreads();

      const float4 hv = ((const float4*)h_s)[ln];
      for (int s = wv8; s < SS; s += 8) {
        const float4 ev = ((const float4*)(enc_s + s * HH))[ln];
        float p = hv.x * ev.x + hv.y * ev.y + hv.z * ev.z + hv.w * ev.w;
        p = wsum(p);
        if (ln == 0) at_s[s] = p * 0.0625f;
      }
      __syncthreads();
      if (wv8 == 0) {
        const float v0 = (ln < len) ? at_s[ln] : -3.0e38f;
        const bool has1 = (ln < 8) && (64 + ln < len);
        const float v1 = has1 ? at_s[64 + ln] : -3.0e38f;
        const float m = wmax(fmaxf(v0, v1));
        const float e0 = (ln < len) ? __expf(v0 - m) : 0.f;
        const float e1 = has1 ? __expf(v1 - m) : 0.f;
        const float inv = 1.f / wsum(e0 + e1);
        at_s[ln] = e0 * inv;
        if (ln < 8) at_s[64 + ln] = e1 * inv;
      }
      __syncthreads();
      if (tid < HH) {
        float acc = 0.f;
#pragma unroll 8
        for (int s = 0; s < SS; ++s) acc += at_s[s] * enc_s[s * HH + tid];
        ctx_s[tid] = acc;
      }
      __syncthreads();
      if (tid < 64) {
        const u64 pk = (u64)f2bf(ctx_s[tid * 4])
                     | ((u64)f2bf(ctx_s[tid * 4 + 1]) << 16)
                     | ((u64)f2bf(ctx_s[tid * 4 + 2]) << 32)
                     | ((u64)f2bf(ctx_s[tid * 4 + 3]) << 48);
        astore(hcat64 + (size_t)(t * 64 + b) * 128 + 64 + tid, pk);
      }
      asm volatile("s_waitcnt vmcnt(0)" ::: "memory");
      __syncthreads();
      if (tid == 0)
        __hip_atomic_fetch_add(F2 + t, 1u, __ATOMIC_RELAXED, __HIP_MEMORY_SCOPE_AGENT);
    }
  } else {
    // ========================== GEMM (128m x 512n items, dbuf staging) ====
    // As 2x8192 [128r][64B] slot^=(row&3); Bs 2x32768 [512r][64B] same swizzle.
    const int gid = role - 1000;
    char* AsB = smem;
    char* BsB = smem + 16384;
    const int ln = tid & 63, w = tid >> 6;
    const int n16 = ln & 15, kgrp = ln >> 4;
    const int wm = w >> 2, wn = w & 3;

    for (int it = gid; it < NITEM; it += NGEMM) {
      const int mc = it / NNT2, ntl = it % NNT2;
      if (tid < 2) {
        while (__hip_atomic_load(F2 + 2 * mc + tid, __ATOMIC_RELAXED,
                                 __HIP_MEMORY_SCOPE_AGENT) < NATTN)
          __builtin_amdgcn_s_sleep(8);
      }
      __syncthreads();
      const int m0 = mc * 128, n0 = ntl * 512;
      float bs[8];
#pragma unroll
      for (int f = 0; f < 8; ++f) {
        const int n = n0 + wn * 128 + f * 16 + n16;
        bs[f] = (n < VV) ? blin[n] : 0.f;
      }
      {
        const int row = tid >> 2, sl = tid & 3;
        g2l16((const char*)hcat64 + (size_t)(m0 + row) * 1024 + ((sl ^ (row & 3)) << 4),
              AsB + tid * 16);
      }
#pragma unroll
      for (int i = 0; i < 4; ++i) {
        const int e = i * 512 + tid, row = e >> 2, sl = e & 3;
        g2l16((const char*)wlin16 + (size_t)(n0 + row) * 1024 + ((sl ^ (row & 3)) << 4),
              BsB + e * 16);
      }
      __syncthreads();

      f32x4 acc[4][8] = {};
      for (int kt = 0; kt < 16; ++kt) {
        const int cur = kt & 1;
        if (kt < 15) {
          const int nb = cur ^ 1;
          const int kb = (kt + 1) * 64;
          {
            const int row = tid >> 2, sl = tid & 3;
            g2l16((const char*)hcat64 + (size_t)(m0 + row) * 1024 + kb + ((sl ^ (row & 3)) << 4),
                  AsB + nb * 8192 + tid * 16);
          }
#pragma unroll
          for (int i = 0; i < 4; ++i) {
            const int e = i * 512 + tid, row = e >> 2, sl = e & 3;
            g2l16((const char*)wlin16 + (size_t)(n0 + row) * 1024 + kb + ((sl ^ (row & 3)) << 4),
                  BsB + nb * 32768 + e * 16);
          }
        }
        short8 af[4], bf[8];
#pragma unroll
        for (int f = 0; f < 4; ++f) {
          const int row = wm * 64 + f * 16 + n16;
          af[f] = *(const short8*)(AsB + cur * 8192 + row * 64 + ((kgrp ^ (row & 3)) << 4));
        }
#pragma unroll
        for (int f = 0; f < 8; ++f) {
          const int row = wn * 128 + f * 16 + n16;
          bf[f] = *(const short8*)(BsB + cur * 32768 + row * 64 + ((kgrp ^ (row & 3)) << 4));
        }
#pragma unroll
        for (int fm = 0; fm < 4; ++fm)
#pragma unroll
          for (int fn = 0; fn < 8; ++fn)
            acc[fm][fn] = __builtin_amdgcn_mfma_f32_16x16x32_bf16(af[fm], bf[fn], acc[fm][fn], 0, 0, 0);
        __syncthreads();
      }

      const int trow = mc * 2 + wm;
#pragma unroll
      for (int fm = 0; fm < 4; ++fm) {
        const int b0 = fm * 16 + kgrp * 4;
#pragma unroll
        for (int fn = 0; fn < 8; ++fn) {
          const int n = n0 + wn * 128 + fn * 16 + n16;
          if (n < VV) {
            float* cp = out + ((size_t)b0 * TT + trow) * VV + n;
#pragma unroll
            for (int r = 0; r < 4; ++r) cp[(size_t)r * TT * VV] = acc[fm][fn][r] + bs[fn];
          }
        }
      }
    }
  }
}

// ------------------------------------------------------------------
extern "C" void kernel_launch(void* const* d_in, const int* in_sizes, int n_in,
                              void* d_out, int out_size, void* d_ws, size_t ws_size,
                              hipStream_t stream) {
  const int*   tok  = (const int*)  d_in[0];
  const float* enc  = (const float*)d_in[1];
  const int*   lens = (const int*)  d_in[2];
  const float* h0   = (const float*)d_in[3];
  const float* c0   = (const float*)d_in[4];
  const float* emb  = (const float*)d_in[5];
  const float* Wih  = (const float*)d_in[6];
  const float* Whh  = (const float*)d_in[7];
  const float* bih  = (const float*)d_in[8];
  const float* bhh  = (const float*)d_in[9];
  const float* Wlin = (const float*)d_in[10];
  const float* blin = (const float*)d_in[11];

  char* ws = (char*)d_ws;
  unsigned short* wlin16 = (unsigned short*)(ws);               // 33,030,144 B (padded 32256 rows)
  u64*            hcat64 = (u64*)           (ws + 33030144);    //  4,718,592 B [t*64+b][128 u64]
  uint4*          xembt  = (uint4*)         (ws + 37748736);    //  1,179,648 B
  uint4*          hex    = (uint4*)         (ws + 38928384);    //  2,392,064 B
  unsigned int*   sync   = (unsigned int*)  (ws + 41320448);    //      2,048 B
  float* out = (float*)d_out;

  hipMemsetAsync(sync, 0, 2048, stream);
  prep_kernel<<<256, 256, 0, stream>>>(tok, emb, Wlin, xembt, wlin16);
  mega_kernel<<<256, 512, 0, stream>>>(h0, c0, Wih, Whh, bih, bhh, enc, lens,
                                       blin, xembt, wlin16, hex, sync, hcat64, out);
}

// Round 10
// 527.721 us; speedup vs baseline: 1.2215x; 1.0353x over previous
//
#include <hip/hip_runtime.h>

#define BB 64
#define TT 72
#define SS 72
#define EE 128
#define HH 256
#define VV 32000
#define KK 512
#define NB 8          // lstm blocks (one XCD)
#define NATTN 64      // attn blocks (one per batch)
#define NGEMM 184     // gemm blocks
#define NNT2 63       // n-tiles of 512 cols (last one padded)
#define NITEM (36 * NNT2)

using f32x4  = __attribute__((ext_vector_type(4))) float;
using short8 = __attribute__((ext_vector_type(8))) short;
typedef unsigned long long u64;

__device__ __forceinline__ unsigned short f2bf(float f) {
  unsigned u = __float_as_uint(f);
  unsigned r = (u + 0x7fffu + ((u >> 16) & 1u)) >> 16;
  return (unsigned short)r;
}
__device__ __forceinline__ float bf2f(unsigned short b) {
  return __uint_as_float(((unsigned)b) << 16);
}
__device__ __forceinline__ float sigm(float x) { return 1.f / (1.f + __expf(-x)); }
__device__ __forceinline__ float tanh_f(float x) { return 1.f - 2.f / (__expf(2.f * x) + 1.f); }

__device__ __forceinline__ float wsum(float v) {
  v += __shfl_xor(v, 1, 64);  v += __shfl_xor(v, 2, 64);  v += __shfl_xor(v, 4, 64);
  v += __shfl_xor(v, 8, 64);  v += __shfl_xor(v, 16, 64); v += __shfl_xor(v, 32, 64);
  return v;
}
__device__ __forceinline__ float wmax(float v) {
  v = fmaxf(v, __shfl_xor(v, 1, 64));  v = fmaxf(v, __shfl_xor(v, 2, 64));
  v = fmaxf(v, __shfl_xor(v, 4, 64));  v = fmaxf(v, __shfl_xor(v, 8, 64));
  v = fmaxf(v, __shfl_xor(v, 16, 64)); v = fmaxf(v, __shfl_xor(v, 32, 64));
  return v;
}
__device__ __forceinline__ void g2l16(const void* g, void* l) {
  __builtin_amdgcn_global_load_lds((const __attribute__((address_space(1))) void*)g,
                                   (__attribute__((address_space(3))) void*)l, 16, 0, 0);
}
__device__ __forceinline__ uint4 pack8(const float4 v0, const float4 v1) {
  uint4 o;
  o.x = f2bf(v0.x) | ((unsigned)f2bf(v0.y) << 16);
  o.y = f2bf(v0.z) | ((unsigned)f2bf(v0.w) << 16);
  o.z = f2bf(v1.x) | ((unsigned)f2bf(v1.y) << 16);
  o.w = f2bf(v1.z) | ((unsigned)f2bf(v1.w) << 16);
  return o;
}
__device__ __forceinline__ u64 aload(const u64* p) {
  return __hip_atomic_load(p, __ATOMIC_RELAXED, __HIP_MEMORY_SCOPE_AGENT);
}
__device__ __forceinline__ void astore(u64* p, u64 v) {
  __hip_atomic_store(p, v, __ATOMIC_RELAXED, __HIP_MEMORY_SCOPE_AGENT);
}

// ------------------------------------------------------------------ prep
__global__ void prep_kernel(const int* __restrict__ tok, const float* __restrict__ emb,
                            const float* __restrict__ Wlin,
                            uint4* __restrict__ xembt, unsigned short* __restrict__ wlin16) {
  const int bid = blockIdx.x, tid = threadIdx.x;
  if (bid < 18) {
    for (int e = bid * 256 + tid; e < TT * 16 * 64; e += 18 * 256) {
      const int b = e & 63, kcx = (e >> 6) & 15, t = e >> 10;
      const int tk = tok[b * TT + t];
      const float4* s = (const float4*)(emb + (size_t)tk * EE + kcx * 8);
      xembt[e] = pack8(s[0], s[1]);
    }
  } else {
    const int n4 = (VV * KK) / 4;
    for (int i = (bid - 18) * 256 + tid; i < n4; i += 238 * 256) {
      float4 v = ((const float4*)Wlin)[i];
      ushort4 o;
      o.x = f2bf(v.x); o.y = f2bf(v.y); o.z = f2bf(v.z); o.w = f2bf(v.w);
      ((ushort4*)wlin16)[i] = o;
    }
  }
}

// ------------------------------------------------------------------ mega
__global__ __launch_bounds__(512) void mega_kernel(
    const float* __restrict__ h0, const float* __restrict__ c0,
    const float* __restrict__ Wih, const float* __restrict__ Whh,
    const float* __restrict__ bih, const float* __restrict__ bhh,
    const float* __restrict__ enc, const int* __restrict__ lens,
    const float* __restrict__ blin, const uint4* __restrict__ xembt,
    const unsigned short* __restrict__ wlin16,
    uint4* __restrict__ hex, unsigned int* __restrict__ sync,
    u64* __restrict__ hcat64, float* __restrict__ out) {
  __shared__ __align__(16) char smem[90112];
  __shared__ int s_role;

  const int tid = threadIdx.x;
  unsigned int* flags1 = sync;         // [bk*32] lstm step counters (128B spaced)
  unsigned int* F2     = sync + 256;   // [0..71] attn completion counters
  unsigned int* elect  = sync + 336;   // [0..7] arrivals, [8] winner, [9] roleCtr

  if (tid == 0) {
    unsigned xcd;
    asm volatile("s_getreg_b32 %0, hwreg(20, 0, 8)" : "=s"(xcd));
    xcd &= 7;
    int role = -1;
    const unsigned my = __hip_atomic_fetch_add(elect + xcd, 1u,
                          __ATOMIC_RELAXED, __HIP_MEMORY_SCOPE_AGENT);
    if (my < NB) {
      if (my == NB - 1) {
        unsigned exp = 0;
        __hip_atomic_compare_exchange_strong(elect + 8, &exp, xcd + 1,
            __ATOMIC_RELAXED, __ATOMIC_RELAXED, __HIP_MEMORY_SCOPE_AGENT);
      }
      unsigned wv;
      while ((wv = __hip_atomic_load(elect + 8, __ATOMIC_RELAXED,
                                     __HIP_MEMORY_SCOPE_AGENT)) == 0)
        __builtin_amdgcn_s_sleep(1);
      if (wv == xcd + 1) role = (int)my;
    }
    if (role < 0) {
      const unsigned idx = __hip_atomic_fetch_add(elect + 9, 1u,
                             __ATOMIC_RELAXED, __HIP_MEMORY_SCOPE_AGENT);
      role = (idx < NATTN) ? (100 + (int)idx) : (1000 + (int)(idx - NATTN));
    }
    s_role = role;
  }
  __syncthreads();
  const int role = s_role;

  if (role < NB) {
    // ========================== LSTM: 8 blocks, 32 j each =================
    // Counted-vmcnt schedule: x loads || poll || h loads; x-MFMAs run under
    // the h-load shadow (vmcnt(4) + raw barrier), then vmcnt(0) + barrier,
    // h-MFMAs, in-register pointwise, astore, drain, barrier, flag.
    const int bk = role;
    uint4* hx = (uint4*)smem;                 // 49152 B: kc<32 h, kc>=32 x
    float* biasL = (float*)(smem + 49152);    // 512 B
    const int ln = tid & 63, w = tid >> 6;
    const int n16 = ln & 15, kgrp = ln >> 4;
    const int wj = w >> 2, wb = w & 3;
    u64* hexq = (u64*)hex;

    short8 wf[4][12];
#pragma unroll
    for (int g = 0; g < 4; ++g) {
      const int row = g * HH + bk * 32 + wj * 16 + n16;
#pragma unroll
      for (int kt = 0; kt < 12; ++kt) {
        const float* src = (kt < 8) ? (Whh + (size_t)row * HH + kt * 32 + kgrp * 8)
                                    : (Wih + (size_t)row * EE + (kt - 8) * 32 + kgrp * 8);
        const float4 v0 = ((const float4*)src)[0];
        const float4 v1 = ((const float4*)src)[1];
        short8 wv;
        wv[0]=(short)f2bf(v0.x); wv[1]=(short)f2bf(v0.y); wv[2]=(short)f2bf(v0.z); wv[3]=(short)f2bf(v0.w);
        wv[4]=(short)f2bf(v1.x); wv[5]=(short)f2bf(v1.y); wv[6]=(short)f2bf(v1.z); wv[7]=(short)f2bf(v1.w);
        wf[g][kt] = wv;
      }
    }
    if (tid < 128) {
      const int wj2 = tid >> 6, kg2 = (tid >> 4) & 3, g2 = (tid >> 2) & 3, r2 = tid & 3;
      const int row = g2 * HH + bk * 32 + wj2 * 16 + kg2 * 4 + r2;
      biasL[tid] = bih[row] + bhh[row];
    }
    const int batch = wb * 16 + n16;
    const int j0 = bk * 32 + wj * 16 + kgrp * 4;
    float creg[4];
    {
      const float4 cv = *(const float4*)(c0 + (size_t)batch * HH + j0);
      creg[0] = cv.x; creg[1] = cv.y; creg[2] = cv.z; creg[3] = cv.w;
    }
#pragma unroll
    for (int i = 0; i < 4; ++i) {
      const int e = i * 512 + tid;
      const int kc = e >> 6, b = e & 63;
      const float* src = h0 + (size_t)b * HH + kc * 8;
      hx[kc * 64 + b] = pack8(((const float4*)src)[0], ((const float4*)src)[1]);
    }
    __syncthreads();

    const int kcq  = bk * 4 + wj * 2 + (kgrp >> 1);
    const int half = kgrp & 1;

    for (int t = 0; t < TT; ++t) {
      // x loads (recurrence-independent)
#pragma unroll
      for (int i = 0; i < 2; ++i) {
        const int e = i * 512 + tid;
        g2l16(xembt + (size_t)t * 1024 + e, (char*)hx + (size_t)(2048 + e) * 16);
      }
      if (t > 0) {
        // wave-local poll: no block barrier between flag and h-issue
        for (;;) {
          unsigned f = 0xffffffffu;
          if (ln < NB) f = __hip_atomic_load(flags1 + ln * 32, __ATOMIC_RELAXED,
                                             __HIP_MEMORY_SCOPE_AGENT);
          if ((__ballot(f >= (unsigned)t) & 0xffull) == 0xffull) break;
          __builtin_amdgcn_s_sleep(1);
        }
#pragma unroll
        for (int i = 0; i < 4; ++i) {
          const int e = i * 512 + tid;
          g2l16(hex + (size_t)t * 2048 + e, (char*)hx + (size_t)e * 16);
        }
        asm volatile("s_waitcnt vmcnt(4)" ::: "memory");   // own x landed, h in flight
      } else {
        asm volatile("s_waitcnt vmcnt(0)" ::: "memory");
      }
      __builtin_amdgcn_sched_barrier(0);
      __builtin_amdgcn_s_barrier();                        // everyone's x landed

      f32x4 a0 = {0,0,0,0}, a1 = a0, a2 = a0, a3 = a0;
      // x-part MFMAs under the h-load shadow
#pragma unroll
      for (int kt = 8; kt < 12; ++kt) {
        const short8 b = *(const short8*)&hx[(kt * 4 + kgrp) * 64 + batch];
        a0 = __builtin_amdgcn_mfma_f32_16x16x32_bf16(wf[0][kt], b, a0, 0, 0, 0);
        a1 = __builtin_amdgcn_mfma_f32_16x16x32_bf16(wf[1][kt], b, a1, 0, 0, 0);
        a2 = __builtin_amdgcn_mfma_f32_16x16x32_bf16(wf[2][kt], b, a2, 0, 0, 0);
        a3 = __builtin_amdgcn_mfma_f32_16x16x32_bf16(wf[3][kt], b, a3, 0, 0, 0);
      }
      asm volatile("s_waitcnt vmcnt(0)" ::: "memory");     // own h landed
      __builtin_amdgcn_sched_barrier(0);
      __builtin_amdgcn_s_barrier();                        // everyone's h landed
#pragma unroll
      for (int kt = 0; kt < 8; ++kt) {
        const short8 b = *(const short8*)&hx[(kt * 4 + kgrp) * 64 + batch];
        a0 = __builtin_amdgcn_mfma_f32_16x16x32_bf16(wf[0][kt], b, a0, 0, 0, 0);
        a1 = __builtin_amdgcn_mfma_f32_16x16x32_bf16(wf[1][kt], b, a1, 0, 0, 0);
        a2 = __builtin_amdgcn_mfma_f32_16x16x32_bf16(wf[2][kt], b, a2, 0, 0, 0);
        a3 = __builtin_amdgcn_mfma_f32_16x16x32_bf16(wf[3][kt], b, a3, 0, 0, 0);
      }

      const float4 b0 = *(const float4*)&biasL[wj * 64 + kgrp * 16 + 0];
      const float4 b1 = *(const float4*)&biasL[wj * 64 + kgrp * 16 + 4];
      const float4 b2 = *(const float4*)&biasL[wj * 64 + kgrp * 16 + 8];
      const float4 b3 = *(const float4*)&biasL[wj * 64 + kgrp * 16 + 12];
      const float bi[4] = {b0.x, b0.y, b0.z, b0.w};
      const float bf_[4] = {b1.x, b1.y, b1.z, b1.w};
      const float bg[4] = {b2.x, b2.y, b2.z, b2.w};
      const float bo[4] = {b3.x, b3.y, b3.z, b3.w};
      u64 pk = 0;
#pragma unroll
      for (int r = 0; r < 4; ++r) {
        const float iv = a0[r] + bi[r], fv = a1[r] + bf_[r],
                    gv = a2[r] + bg[r], ov = a3[r] + bo[r];
        const float cn = sigm(fv) * creg[r] + sigm(iv) * tanh_f(gv);
        creg[r] = cn;
        const float hv = sigm(ov) * tanh_f(cn);
        pk |= (u64)f2bf(hv) << (16 * r);
      }
      astore(hexq + ((size_t)(t + 1) * 2048 + kcq * 64 + batch) * 2 + half, pk);
      asm volatile("s_waitcnt vmcnt(0)" ::: "memory");
      __builtin_amdgcn_s_barrier();                        // all stores drained
      if (tid == 0)
        __hip_atomic_store(flags1 + bk * 32, (unsigned)(t + 1),
                           __ATOMIC_RELAXED, __HIP_MEMORY_SCOPE_AGENT);
    }
  } else if (role < 1000) {
    // ========================== ATTN (one block per batch) ================
    const int b = role - 100;
    float* enc_s = (float*)smem;
    float* h_s   = (float*)(smem + 73728);
    float* at_s  = (float*)(smem + 74752);
    float* ctx_s = (float*)(smem + 75776);
    const int wv8 = tid >> 6, ln = tid & 63;
    const int len = lens[b];
    const u64* hexq = (const u64*)hex;
    {
      const float4* src = (const float4*)(enc + (size_t)b * SS * HH);
      float4* dst = (float4*)enc_s;
      for (int i = tid; i < SS * HH / 4; i += 512) dst[i] = src[i];
    }
    __syncthreads();

    for (int t = 0; t < TT; ++t) {
      if (tid < NB) {
        while (__hip_atomic_load(flags1 + tid * 32, __ATOMIC_RELAXED,
                                 __HIP_MEMORY_SCOPE_AGENT) < (unsigned)(t + 1))
          __builtin_amdgcn_s_sleep(2);
      }
      __syncthreads();
      if (tid < 64) {
        const int kc = tid >> 1, hf = tid & 1;
        // plain load: first touch of this line per run is post-flag; replay-stale
        // lines hold identical bytes
        const u64 v = hexq[((size_t)(t + 1) * 2048 + kc * 64 + b) * 2 + hf];
        const int j0 = kc * 8 + hf * 4;
        h_s[j0]     = bf2f((unsigned short)v);
        h_s[j0 + 1] = bf2f((unsigned short)(v >> 16));
        h_s[j0 + 2] = bf2f((unsigned short)(v >> 32));
        h_s[j0 + 3] = bf2f((unsigned short)(v >> 48));
        astore(hcat64 + (size_t)(t * 64 + b) * 128 + tid, v);   // h-half of hcat
      }
      __syncthreads();

      const float4 hv = ((const float4*)h_s)[ln];
      for (int s = wv8; s < SS; s += 8) {
        const float4 ev = ((const float4*)(enc_s + s * HH))[ln];
        float p = hv.x * ev.x + hv.y * ev.y + hv.z * ev.z + hv.w * ev.w;
        p = wsum(p);
        if (ln == 0) at_s[s] = p * 0.0625f;
      }
      __syncthreads();
      if (wv8 == 0) {
        const float v0 = (ln < len) ? at_s[ln] : -3.0e38f;
        const bool has1 = (ln < 8) && (64 + ln < len);
        const float v1 = has1 ? at_s[64 + ln] : -3.0e38f;
        const float m = wmax(fmaxf(v0, v1));
        const float e0 = (ln < len) ? __expf(v0 - m) : 0.f;
        const float e1 = has1 ? __expf(v1 - m) : 0.f;
        const float inv = 1.f / wsum(e0 + e1);
        at_s[ln] = e0 * inv;
        if (ln < 8) at_s[64 + ln] = e1 * inv;
      }
      __syncthreads();
      if (tid < HH) {
        float acc = 0.f;
#pragma unroll 8
        for (int s = 0; s < SS; ++s) acc += at_s[s] * enc_s[s * HH + tid];
        ctx_s[tid] = acc;
      }
      __syncthreads();
      if (tid < 64) {
        const u64 pk = (u64)f2bf(ctx_s[tid * 4])
                     | ((u64)f2bf(ctx_s[tid * 4 + 1]) << 16)
                     | ((u64)f2bf(ctx_s[tid * 4 + 2]) << 32)
                     | ((u64)f2bf(ctx_s[tid * 4 + 3]) << 48);
        astore(hcat64 + (size_t)(t * 64 + b) * 128 + 64 + tid, pk);
      }
      asm volatile("s_waitcnt vmcnt(0)" ::: "memory");
      __syncthreads();
      if (tid == 0)
        __hip_atomic_fetch_add(F2 + t, 1u, __ATOMIC_RELAXED, __HIP_MEMORY_SCOPE_AGENT);
    }
  } else {
    // ========================== GEMM (128m x 512n items, dbuf staging) ====
    const int gid = role - 1000;
    char* AsB = smem;
    char* BsB = smem + 16384;
    const int ln = tid & 63, w = tid >> 6;
    const int n16 = ln & 15, kgrp = ln >> 4;
    const int wm = w >> 2, wn = w & 3;

    for (int it = gid; it < NITEM; it += NGEMM) {
      const int mc = it / NNT2, ntl = it % NNT2;
      if (tid < 2) {
        while (__hip_atomic_load(F2 + 2 * mc + tid, __ATOMIC_RELAXED,
                                 __HIP_MEMORY_SCOPE_AGENT) < NATTN)
          __builtin_amdgcn_s_sleep(16);
      }
      __syncthreads();
      const int m0 = mc * 128, n0 = ntl * 512;
      float bs[8];
#pragma unroll
      for (int f = 0; f < 8; ++f) {
        const int n = n0 + wn * 128 + f * 16 + n16;
        bs[f] = (n < VV) ? blin[n] : 0.f;
      }
      {
        const int row = tid >> 2, sl = tid & 3;
        g2l16((const char*)hcat64 + (size_t)(m0 + row) * 1024 + ((sl ^ (row & 3)) << 4),
              AsB + tid * 16);
      }
#pragma unroll
      for (int i = 0; i < 4; ++i) {
        const int e = i * 512 + tid, row = e >> 2, sl = e & 3;
        g2l16((const char*)wlin16 + (size_t)(n0 + row) * 1024 + ((sl ^ (row & 3)) << 4),
              BsB + e * 16);
      }
      __syncthreads();

      f32x4 acc[4][8] = {};
      for (int kt = 0; kt < 16; ++kt) {
        const int cur = kt & 1;
        if (kt < 15) {
          const int nb = cur ^ 1;
          const int kb = (kt + 1) * 64;
          {
            const int row = tid >> 2, sl = tid & 3;
            g2l16((const char*)hcat64 + (size_t)(m0 + row) * 1024 + kb + ((sl ^ (row & 3)) << 4),
                  AsB + nb * 8192 + tid * 16);
          }
#pragma unroll
          for (int i = 0; i < 4; ++i) {
            const int e = i * 512 + tid, row = e >> 2, sl = e & 3;
            g2l16((const char*)wlin16 + (size_t)(n0 + row) * 1024 + kb + ((sl ^ (row & 3)) << 4),
                  BsB + nb * 32768 + e * 16);
          }
        }
        short8 af[4], bf[8];
#pragma unroll
        for (int f = 0; f < 4; ++f) {
          const int row = wm * 64 + f * 16 + n16;
          af[f] = *(const short8*)(AsB + cur * 8192 + row * 64 + ((kgrp ^ (row & 3)) << 4));
        }
#pragma unroll
        for (int f = 0; f < 8; ++f) {
          const int row = wn * 128 + f * 16 + n16;
          bf[f] = *(const short8*)(BsB + cur * 32768 + row * 64 + ((kgrp ^ (row & 3)) << 4));
        }
#pragma unroll
        for (int fm = 0; fm < 4; ++fm)
#pragma unroll
          for (int fn = 0; fn < 8; ++fn)
            acc[fm][fn] = __builtin_amdgcn_mfma_f32_16x16x32_bf16(af[fm], bf[fn], acc[fm][fn], 0, 0, 0);
        __syncthreads();
      }

      const int trow = mc * 2 + wm;
#pragma unroll
      for (int fm = 0; fm < 4; ++fm) {
        const int b0 = fm * 16 + kgrp * 4;
#pragma unroll
        for (int fn = 0; fn < 8; ++fn) {
          const int n = n0 + wn * 128 + fn * 16 + n16;
          if (n < VV) {
            float* cp = out + ((size_t)b0 * TT + trow) * VV + n;
#pragma unroll
            for (int r = 0; r < 4; ++r) cp[(size_t)r * TT * VV] = acc[fm][fn][r] + bs[fn];
          }
        }
      }
    }
  }
}

// ------------------------------------------------------------------
extern "C" void kernel_launch(void* const* d_in, const int* in_sizes, int n_in,
                              void* d_out, int out_size, void* d_ws, size_t ws_size,
                              hipStream_t stream) {
  const int*   tok  = (const int*)  d_in[0];
  const float* enc  = (const float*)d_in[1];
  const int*   lens = (const int*)  d_in[2];
  const float* h0   = (const float*)d_in[3];
  const float* c0   = (const float*)d_in[4];
  const float* emb  = (const float*)d_in[5];
  const float* Wih  = (const float*)d_in[6];
  const float* Whh  = (const float*)d_in[7];
  const float* bih  = (const float*)d_in[8];
  const float* bhh  = (const float*)d_in[9];
  const float* Wlin = (const float*)d_in[10];
  const float* blin = (const float*)d_in[11];

  char* ws = (char*)d_ws;
  unsigned short* wlin16 = (unsigned short*)(ws);               // 33,030,144 B (padded)
  u64*            hcat64 = (u64*)           (ws + 33030144);    //  4,718,592 B
  uint4*          xembt  = (uint4*)         (ws + 37748736);    //  1,179,648 B
  uint4*          hex    = (uint4*)         (ws + 38928384);    //  2,392,064 B
  unsigned int*   sync   = (unsigned int*)  (ws + 41320448);    //      2,048 B
  float* out = (float*)d_out;

  hipMemsetAsync(sync, 0, 2048, stream);
  prep_kernel<<<256, 256, 0, stream>>>(tok, emb, Wlin, xembt, wlin16);
  mega_kernel<<<256, 512, 0, stream>>>(h0, c0, Wih, Whh, bih, bhh, enc, lens,
                                       blin, xembt, wlin16, hex, sync, hcat64, out);
}

// Round 12
// 523.495 us; speedup vs baseline: 1.2314x; 1.0081x over previous
//
#include <hip/hip_runtime.h>

#define BB 64
#define TT 72
#define SS 72
#define EE 128
#define HH 256
#define VV 32000
#define KK 512
#define NB 8          // lstm blocks (one XCD)
#define NATTN 64      // attn blocks (one per batch)
#define NGEMM 184     // gemm blocks
#define NNT2 63       // n-tiles of 512 cols (last one padded)
#define NITEM (36 * NNT2)

using f32x4  = __attribute__((ext_vector_type(4))) float;
using short8 = __attribute__((ext_vector_type(8))) short;
typedef unsigned long long u64;

__device__ __forceinline__ unsigned short f2bf(float f) {
  unsigned u = __float_as_uint(f);
  unsigned r = (u + 0x7fffu + ((u >> 16) & 1u)) >> 16;
  return (unsigned short)r;
}
__device__ __forceinline__ float bf2f(unsigned short b) {
  return __uint_as_float(((unsigned)b) << 16);
}
__device__ __forceinline__ float sigm(float x) { return 1.f / (1.f + __expf(-x)); }
__device__ __forceinline__ float tanh_f(float x) { return 1.f - 2.f / (__expf(2.f * x) + 1.f); }

__device__ __forceinline__ float wsum(float v) {
  v += __shfl_xor(v, 1, 64);  v += __shfl_xor(v, 2, 64);  v += __shfl_xor(v, 4, 64);
  v += __shfl_xor(v, 8, 64);  v += __shfl_xor(v, 16, 64); v += __shfl_xor(v, 32, 64);
  return v;
}
__device__ __forceinline__ float wmax(float v) {
  v = fmaxf(v, __shfl_xor(v, 1, 64));  v = fmaxf(v, __shfl_xor(v, 2, 64));
  v = fmaxf(v, __shfl_xor(v, 4, 64));  v = fmaxf(v, __shfl_xor(v, 8, 64));
  v = fmaxf(v, __shfl_xor(v, 16, 64)); v = fmaxf(v, __shfl_xor(v, 32, 64));
  return v;
}
__device__ __forceinline__ void g2l16(const void* g, void* l) {
  __builtin_amdgcn_global_load_lds((const __attribute__((address_space(1))) void*)g,
                                   (__attribute__((address_space(3))) void*)l, 16, 0, 0);
}
__device__ __forceinline__ uint4 pack8(const float4 v0, const float4 v1) {
  uint4 o;
  o.x = f2bf(v0.x) | ((unsigned)f2bf(v0.y) << 16);
  o.y = f2bf(v0.z) | ((unsigned)f2bf(v0.w) << 16);
  o.z = f2bf(v1.x) | ((unsigned)f2bf(v1.y) << 16);
  o.w = f2bf(v1.z) | ((unsigned)f2bf(v1.w) << 16);
  return o;
}
__device__ __forceinline__ u64 aload(const u64* p) {
  return __hip_atomic_load(p, __ATOMIC_RELAXED, __HIP_MEMORY_SCOPE_AGENT);
}
__device__ __forceinline__ void astore(u64* p, u64 v) {
  __hip_atomic_store(p, v, __ATOMIC_RELAXED, __HIP_MEMORY_SCOPE_AGENT);
}

// ------------------------------------------------------------------ prep
__global__ void prep_kernel(const int* __restrict__ tok, const float* __restrict__ emb,
                            const float* __restrict__ Wlin,
                            uint4* __restrict__ xembt, unsigned short* __restrict__ wlin16) {
  const int bid = blockIdx.x, tid = threadIdx.x;
  if (bid < 18) {
    for (int e = bid * 256 + tid; e < TT * 16 * 64; e += 18 * 256) {
      const int b = e & 63, kcx = (e >> 6) & 15, t = e >> 10;
      const int tk = tok[b * TT + t];
      const float4* s = (const float4*)(emb + (size_t)tk * EE + kcx * 8);
      xembt[e] = pack8(s[0], s[1]);
    }
  } else {
    const int n4 = (VV * KK) / 4;
    for (int i = (bid - 18) * 256 + tid; i < n4; i += 238 * 256) {
      float4 v = ((const float4*)Wlin)[i];
      ushort4 o;
      o.x = f2bf(v.x); o.y = f2bf(v.y); o.z = f2bf(v.z); o.w = f2bf(v.w);
      ((ushort4*)wlin16)[i] = o;
    }
  }
}

// ------------------------------------------------------------------ mega
// r10 base. Change: attn polls flagsA (separate 64B-spaced lines) so the
// producer-critical flags1 lines are touched only by lstm itself; bigger
// consumer backoffs. All sync primitives unchanged (agent-relaxed atomics).
__global__ __launch_bounds__(512) void mega_kernel(
    const float* __restrict__ h0, const float* __restrict__ c0,
    const float* __restrict__ Wih, const float* __restrict__ Whh,
    const float* __restrict__ bih, const float* __restrict__ bhh,
    const float* __restrict__ enc, const int* __restrict__ lens,
    const float* __restrict__ blin, const uint4* __restrict__ xembt,
    const unsigned short* __restrict__ wlin16,
    uint4* __restrict__ hex, unsigned int* __restrict__ sync,
    u64* __restrict__ hcat64, float* __restrict__ out) {
  __shared__ __align__(16) char smem[90112];
  __shared__ int s_role;

  const int tid = threadIdx.x;
  unsigned int* flags1 = sync;         // [bk*32] lstm step counters (lstm-only)
  unsigned int* F2     = sync + 256;   // [0..71] attn completion counters
  unsigned int* elect  = sync + 336;   // [0..7] arrivals, [8] winner, [9] roleCtr
  unsigned int* flagsA = sync + 384;   // [bk*16] lstm->attn step counters

  if (tid == 0) {
    unsigned xcd;
    asm volatile("s_getreg_b32 %0, hwreg(20, 0, 8)" : "=s"(xcd));
    xcd &= 7;
    int role = -1;
    const unsigned my = __hip_atomic_fetch_add(elect + xcd, 1u,
                          __ATOMIC_RELAXED, __HIP_MEMORY_SCOPE_AGENT);
    if (my < NB) {
      if (my == NB - 1) {
        unsigned exp = 0;
        __hip_atomic_compare_exchange_strong(elect + 8, &exp, xcd + 1,
            __ATOMIC_RELAXED, __ATOMIC_RELAXED, __HIP_MEMORY_SCOPE_AGENT);
      }
      unsigned wv;
      while ((wv = __hip_atomic_load(elect + 8, __ATOMIC_RELAXED,
                                     __HIP_MEMORY_SCOPE_AGENT)) == 0)
        __builtin_amdgcn_s_sleep(1);
      if (wv == xcd + 1) role = (int)my;
    }
    if (role < 0) {
      const unsigned idx = __hip_atomic_fetch_add(elect + 9, 1u,
                             __ATOMIC_RELAXED, __HIP_MEMORY_SCOPE_AGENT);
      role = (idx < NATTN) ? (100 + (int)idx) : (1000 + (int)(idx - NATTN));
    }
    s_role = role;
  }
  __syncthreads();
  const int role = s_role;

  if (role < NB) {
    // ========================== LSTM: 8 blocks, 32 j each =================
    const int bk = role;
    uint4* hx = (uint4*)smem;                 // 49152 B: kc<32 h, kc>=32 x
    float* biasL = (float*)(smem + 49152);    // 512 B
    const int ln = tid & 63, w = tid >> 6;
    const int n16 = ln & 15, kgrp = ln >> 4;
    const int wj = w >> 2, wb = w & 3;
    u64* hexq = (u64*)hex;

    short8 wf[4][12];
#pragma unroll
    for (int g = 0; g < 4; ++g) {
      const int row = g * HH + bk * 32 + wj * 16 + n16;
#pragma unroll
      for (int kt = 0; kt < 12; ++kt) {
        const float* src = (kt < 8) ? (Whh + (size_t)row * HH + kt * 32 + kgrp * 8)
                                    : (Wih + (size_t)row * EE + (kt - 8) * 32 + kgrp * 8);
        const float4 v0 = ((const float4*)src)[0];
        const float4 v1 = ((const float4*)src)[1];
        short8 wv;
        wv[0]=(short)f2bf(v0.x); wv[1]=(short)f2bf(v0.y); wv[2]=(short)f2bf(v0.z); wv[3]=(short)f2bf(v0.w);
        wv[4]=(short)f2bf(v1.x); wv[5]=(short)f2bf(v1.y); wv[6]=(short)f2bf(v1.z); wv[7]=(short)f2bf(v1.w);
        wf[g][kt] = wv;
      }
    }
    if (tid < 128) {
      const int wj2 = tid >> 6, kg2 = (tid >> 4) & 3, g2 = (tid >> 2) & 3, r2 = tid & 3;
      const int row = g2 * HH + bk * 32 + wj2 * 16 + kg2 * 4 + r2;
      biasL[tid] = bih[row] + bhh[row];
    }
    const int batch = wb * 16 + n16;
    const int j0 = bk * 32 + wj * 16 + kgrp * 4;
    float creg[4];
    {
      const float4 cv = *(const float4*)(c0 + (size_t)batch * HH + j0);
      creg[0] = cv.x; creg[1] = cv.y; creg[2] = cv.z; creg[3] = cv.w;
    }
#pragma unroll
    for (int i = 0; i < 4; ++i) {
      const int e = i * 512 + tid;
      const int kc = e >> 6, b = e & 63;
      const float* src = h0 + (size_t)b * HH + kc * 8;
      hx[kc * 64 + b] = pack8(((const float4*)src)[0], ((const float4*)src)[1]);
    }
    __syncthreads();

    const int kcq  = bk * 4 + wj * 2 + (kgrp >> 1);
    const int half = kgrp & 1;

    for (int t = 0; t < TT; ++t) {
      // x loads (recurrence-independent)
#pragma unroll
      for (int i = 0; i < 2; ++i) {
        const int e = i * 512 + tid;
        g2l16(xembt + (size_t)t * 1024 + e, (char*)hx + (size_t)(2048 + e) * 16);
      }
      if (t > 0) {
        // wave-local poll: no block barrier between flag and h-issue
        for (;;) {
          unsigned f = 0xffffffffu;
          if (ln < NB) f = __hip_atomic_load(flags1 + ln * 32, __ATOMIC_RELAXED,
                                             __HIP_MEMORY_SCOPE_AGENT);
          if ((__ballot(f >= (unsigned)t) & 0xffull) == 0xffull) break;
          __builtin_amdgcn_s_sleep(1);
        }
#pragma unroll
        for (int i = 0; i < 4; ++i) {
          const int e = i * 512 + tid;
          g2l16(hex + (size_t)t * 2048 + e, (char*)hx + (size_t)e * 16);
        }
        asm volatile("s_waitcnt vmcnt(4)" ::: "memory");   // own x landed, h in flight
      } else {
        asm volatile("s_waitcnt vmcnt(0)" ::: "memory");
      }
      __builtin_amdgcn_sched_barrier(0);
      __builtin_amdgcn_s_barrier();                        // everyone's x landed

      f32x4 a0 = {0,0,0,0}, a1 = a0, a2 = a0, a3 = a0;
      // x-part MFMAs under the h-load shadow
#pragma unroll
      for (int kt = 8; kt < 12; ++kt) {
        const short8 b = *(const short8*)&hx[(kt * 4 + kgrp) * 64 + batch];
        a0 = __builtin_amdgcn_mfma_f32_16x16x32_bf16(wf[0][kt], b, a0, 0, 0, 0);
        a1 = __builtin_amdgcn_mfma_f32_16x16x32_bf16(wf[1][kt], b, a1, 0, 0, 0);
        a2 = __builtin_amdgcn_mfma_f32_16x16x32_bf16(wf[2][kt], b, a2, 0, 0, 0);
        a3 = __builtin_amdgcn_mfma_f32_16x16x32_bf16(wf[3][kt], b, a3, 0, 0, 0);
      }
      asm volatile("s_waitcnt vmcnt(0)" ::: "memory");     // own h landed
      __builtin_amdgcn_sched_barrier(0);
      __builtin_amdgcn_s_barrier();                        // everyone's h landed
#pragma unroll
      for (int kt = 0; kt < 8; ++kt) {
        const short8 b = *(const short8*)&hx[(kt * 4 + kgrp) * 64 + batch];
        a0 = __builtin_amdgcn_mfma_f32_16x16x32_bf16(wf[0][kt], b, a0, 0, 0, 0);
        a1 = __builtin_amdgcn_mfma_f32_16x16x32_bf16(wf[1][kt], b, a1, 0, 0, 0);
        a2 = __builtin_amdgcn_mfma_f32_16x16x32_bf16(wf[2][kt], b, a2, 0, 0, 0);
        a3 = __builtin_amdgcn_mfma_f32_16x16x32_bf16(wf[3][kt], b, a3, 0, 0, 0);
      }

      const float4 b0 = *(const float4*)&biasL[wj * 64 + kgrp * 16 + 0];
      const float4 b1 = *(const float4*)&biasL[wj * 64 + kgrp * 16 + 4];
      const float4 b2 = *(const float4*)&biasL[wj * 64 + kgrp * 16 + 8];
      const float4 b3 = *(const float4*)&biasL[wj * 64 + kgrp * 16 + 12];
      const float bi[4] = {b0.x, b0.y, b0.z, b0.w};
      const float bf_[4] = {b1.x, b1.y, b1.z, b1.w};
      const float bg[4] = {b2.x, b2.y, b2.z, b2.w};
      const float bo[4] = {b3.x, b3.y, b3.z, b3.w};
      u64 pk = 0;
#pragma unroll
      for (int r = 0; r < 4; ++r) {
        const float iv = a0[r] + bi[r], fv = a1[r] + bf_[r],
                    gv = a2[r] + bg[r], ov = a3[r] + bo[r];
        const float cn = sigm(fv) * creg[r] + sigm(iv) * tanh_f(gv);
        creg[r] = cn;
        const float hv = sigm(ov) * tanh_f(cn);
        pk |= (u64)f2bf(hv) << (16 * r);
      }
      astore(hexq + ((size_t)(t + 1) * 2048 + kcq * 64 + batch) * 2 + half, pk);
      asm volatile("s_waitcnt vmcnt(0)" ::: "memory");
      __builtin_amdgcn_s_barrier();                        // all stores drained
      if (tid == 0) {
        __hip_atomic_store(flags1 + bk * 32, (unsigned)(t + 1),
                           __ATOMIC_RELAXED, __HIP_MEMORY_SCOPE_AGENT);
        __hip_atomic_store(flagsA + bk * 16, (unsigned)(t + 1),
                           __ATOMIC_RELAXED, __HIP_MEMORY_SCOPE_AGENT);
      }
    }
  } else if (role < 1000) {
    // ========================== ATTN (one block per batch) ================
    const int b = role - 100;
    float* enc_s = (float*)smem;
    float* h_s   = (float*)(smem + 73728);
    float* at_s  = (float*)(smem + 74752);
    float* ctx_s = (float*)(smem + 75776);
    const int wv8 = tid >> 6, ln = tid & 63;
    const int len = lens[b];
    const u64* hexq = (const u64*)hex;
    {
      const float4* src = (const float4*)(enc + (size_t)b * SS * HH);
      float4* dst = (float4*)enc_s;
      for (int i = tid; i < SS * HH / 4; i += 512) dst[i] = src[i];
    }
    __syncthreads();

    for (int t = 0; t < TT; ++t) {
      if (tid < NB) {
        while (__hip_atomic_load(flagsA + tid * 16, __ATOMIC_RELAXED,
                                 __HIP_MEMORY_SCOPE_AGENT) < (unsigned)(t + 1))
          __builtin_amdgcn_s_sleep(8);
      }
      __syncthreads();
      if (tid < 64) {
        const int kc = tid >> 1, hf = tid & 1;
        // plain load: first touch of this line per run is post-flag; replay-stale
        // lines hold identical bytes
        const u64 v = hexq[((size_t)(t + 1) * 2048 + kc * 64 + b) * 2 + hf];
        const int j0 = kc * 8 + hf * 4;
        h_s[j0]     = bf2f((unsigned short)v);
        h_s[j0 + 1] = bf2f((unsigned short)(v >> 16));
        h_s[j0 + 2] = bf2f((unsigned short)(v >> 32));
        h_s[j0 + 3] = bf2f((unsigned short)(v >> 48));
        astore(hcat64 + (size_t)(t * 64 + b) * 128 + tid, v);   // h-half of hcat
      }
      __syncthreads();

      const float4 hv = ((const float4*)h_s)[ln];
      for (int s = wv8; s < SS; s += 8) {
        const float4 ev = ((const float4*)(enc_s + s * HH))[ln];
        float p = hv.x * ev.x + hv.y * ev.y + hv.z * ev.z + hv.w * ev.w;
        p = wsum(p);
        if (ln == 0) at_s[s] = p * 0.0625f;
      }
      __syncthreads();
      if (wv8 == 0) {
        const float v0 = (ln < len) ? at_s[ln] : -3.0e38f;
        const bool has1 = (ln < 8) && (64 + ln < len);
        const float v1 = has1 ? at_s[64 + ln] : -3.0e38f;
        const float m = wmax(fmaxf(v0, v1));
        const float e0 = (ln < len) ? __expf(v0 - m) : 0.f;
        const float e1 = has1 ? __expf(v1 - m) : 0.f;
        const float inv = 1.f / wsum(e0 + e1);
        at_s[ln] = e0 * inv;
        if (ln < 8) at_s[64 + ln] = e1 * inv;
      }
      __syncthreads();
      if (tid < HH) {
        float acc = 0.f;
#pragma unroll 8
        for (int s = 0; s < SS; ++s) acc += at_s[s] * enc_s[s * HH + tid];
        ctx_s[tid] = acc;
      }
      __syncthreads();
      if (tid < 64) {
        const u64 pk = (u64)f2bf(ctx_s[tid * 4])
                     | ((u64)f2bf(ctx_s[tid * 4 + 1]) << 16)
                     | ((u64)f2bf(ctx_s[tid * 4 + 2]) << 32)
                     | ((u64)f2bf(ctx_s[tid * 4 + 3]) << 48);
        astore(hcat64 + (size_t)(t * 64 + b) * 128 + 64 + tid, pk);
      }
      asm volatile("s_waitcnt vmcnt(0)" ::: "memory");
      __syncthreads();
      if (tid == 0)
        __hip_atomic_fetch_add(F2 + t, 1u, __ATOMIC_RELAXED, __HIP_MEMORY_SCOPE_AGENT);
    }
  } else {
    // ========================== GEMM (128m x 512n items, dbuf staging) ====
    const int gid = role - 1000;
    char* AsB = smem;
    char* BsB = smem + 16384;
    const int ln = tid & 63, w = tid >> 6;
    const int n16 = ln & 15, kgrp = ln >> 4;
    const int wm = w >> 2, wn = w & 3;

    for (int it = gid; it < NITEM; it += NGEMM) {
      const int mc = it / NNT2, ntl = it % NNT2;
      if (tid < 2) {
        while (__hip_atomic_load(F2 + 2 * mc + tid, __ATOMIC_RELAXED,
                                 __HIP_MEMORY_SCOPE_AGENT) < NATTN)
          __builtin_amdgcn_s_sleep(32);
      }
      __syncthreads();
      const int m0 = mc * 128, n0 = ntl * 512;
      float bs[8];
#pragma unroll
      for (int f = 0; f < 8; ++f) {
        const int n = n0 + wn * 128 + f * 16 + n16;
        bs[f] = (n < VV) ? blin[n] : 0.f;
      }
      {
        const int row = tid >> 2, sl = tid & 3;
        g2l16((const char*)hcat64 + (size_t)(m0 + row) * 1024 + ((sl ^ (row & 3)) << 4),
              AsB + tid * 16);
      }
#pragma unroll
      for (int i = 0; i < 4; ++i) {
        const int e = i * 512 + tid, row = e >> 2, sl = e & 3;
        g2l16((const char*)wlin16 + (size_t)(n0 + row) * 1024 + ((sl ^ (row & 3)) << 4),
              BsB + e * 16);
      }
      __syncthreads();

      f32x4 acc[4][8] = {};
      for (int kt = 0; kt < 16; ++kt) {
        const int cur = kt & 1;
        if (kt < 15) {
          const int nb = cur ^ 1;
          const int kb = (kt + 1) * 64;
          {
            const int row = tid >> 2, sl = tid & 3;
            g2l16((const char*)hcat64 + (size_t)(m0 + row) * 1024 + kb + ((sl ^ (row & 3)) << 4),
                  AsB + nb * 8192 + tid * 16);
          }
#pragma unroll
          for (int i = 0; i < 4; ++i) {
            const int e = i * 512 + tid, row = e >> 2, sl = e & 3;
            g2l16((const char*)wlin16 + (size_t)(n0 + row) * 1024 + kb + ((sl ^ (row & 3)) << 4),
                  BsB + nb * 32768 + e * 16);
          }
        }
        short8 af[4], bf[8];
#pragma unroll
        for (int f = 0; f < 4; ++f) {
          const int row = wm * 64 + f * 16 + n16;
          af[f] = *(const short8*)(AsB + cur * 8192 + row * 64 + ((kgrp ^ (row & 3)) << 4));
        }
#pragma unroll
        for (int f = 0; f < 8; ++f) {
          const int row = wn * 128 + f * 16 + n16;
          bf[f] = *(const short8*)(BsB + cur * 32768 + row * 64 + ((kgrp ^ (row & 3)) << 4));
        }
#pragma unroll
        for (int fm = 0; fm < 4; ++fm)
#pragma unroll
          for (int fn = 0; fn < 8; ++fn)
            acc[fm][fn] = __builtin_amdgcn_mfma_f32_16x16x32_bf16(af[fm], bf[fn], acc[fm][fn], 0, 0, 0);
        __syncthreads();
      }

      const int trow = mc * 2 + wm;
#pragma unroll
      for (int fm = 0; fm < 4; ++fm) {
        const int b0 = fm * 16 + kgrp * 4;
#pragma unroll
        for (int fn = 0; fn < 8; ++fn) {
          const int n = n0 + wn * 128 + fn * 16 + n16;
          if (n < VV) {
            float* cp = out + ((size_t)b0 * TT + trow) * VV + n;
#pragma unroll
            for (int r = 0; r < 4; ++r) cp[(size_t)r * TT * VV] = acc[fm][fn][r] + bs[fn];
          }
        }
      }
    }
  }
}

// ------------------------------------------------------------------
extern "C" void kernel_launch(void* const* d_in, const int* in_sizes, int n_in,
                              void* d_out, int out_size, void* d_ws, size_t ws_size,
                              hipStream_t stream) {
  const int*   tok  = (const int*)  d_in[0];
  const float* enc  = (const float*)d_in[1];
  const int*   lens = (const int*)  d_in[2];
  const float* h0   = (const float*)d_in[3];
  const float* c0   = (const float*)d_in[4];
  const float* emb  = (const float*)d_in[5];
  const float* Wih  = (const float*)d_in[6];
  const float* Whh  = (const float*)d_in[7];
  const float* bih  = (const float*)d_in[8];
  const float* bhh  = (const float*)d_in[9];
  const float* Wlin = (const float*)d_in[10];
  const float* blin = (const float*)d_in[11];

  char* ws = (char*)d_ws;
  unsigned short* wlin16 = (unsigned short*)(ws);               // 33,030,144 B (padded)
  u64*            hcat64 = (u64*)           (ws + 33030144);    //  4,718,592 B
  uint4*          xembt  = (uint4*)         (ws + 37748736);    //  1,179,648 B
  uint4*          hex    = (uint4*)         (ws + 38928384);    //  2,392,064 B
  unsigned int*   sync   = (unsigned int*)  (ws + 41320448);    //      2,048 B
  float* out = (float*)d_out;

  hipMemsetAsync(sync, 0, 2048, stream);
  prep_kernel<<<256, 256, 0, stream>>>(tok, emb, Wlin, xembt, wlin16);
  mega_kernel<<<256, 512, 0, stream>>>(h0, c0, Wih, Whh, bih, bhh, enc, lens,
                                       blin, xembt, wlin16, hex, sync, hcat64, out);
}